// Round 1
// baseline (715.245 us; speedup 1.0000x reference)
//
#include <hip/hip_runtime.h>
#include <math.h>

#define BB 64
#define SS 4096
#define DD 512

// t[b,d] = sum_k topic[b,k] * W[k,d]
__global__ __launch_bounds__(256) void tW_kernel(const float* __restrict__ topic,
                                                 const float* __restrict__ W,
                                                 float* __restrict__ t) {
    __shared__ float tp[DD];
    const int b = blockIdx.x >> 1;                       // 2 blocks per batch row
    const int d = ((blockIdx.x & 1) << 8) + threadIdx.x; // 256-wide d chunk
    for (int i = threadIdx.x; i < DD; i += 256) tp[i] = topic[b * DD + i];
    __syncthreads();
    float acc = 0.f;
#pragma unroll 8
    for (int k = 0; k < DD; ++k) acc += tp[k] * W[k * DD + d];
    t[b * DD + d] = acc;
}

// scores[b,s] = t[b] . seq[b,s] + bias   (one wave per score, 32 scores/block)
__global__ __launch_bounds__(256) void scores_kernel(const float* __restrict__ t,
                                                     const float* __restrict__ seq,
                                                     const float* __restrict__ bias,
                                                     float* __restrict__ scores) {
    const int b    = blockIdx.y;
    const int s0   = blockIdx.x << 5;
    const int wave = threadIdx.x >> 6;
    const int lane = threadIdx.x & 63;

    const float4* trow = (const float4*)(t + b * DD);
    const float4 ta = trow[lane];        // d = 4*lane      .. +3
    const float4 tb = trow[lane + 64];   // d = 256+4*lane  .. +3
    const float bs = bias[0];

    for (int i = wave; i < 32; i += 4) {
        const int s = s0 + i;
        const float4* p = (const float4*)(seq + ((size_t)b * SS + s) * DD);
        const float4 a = p[lane];
        const float4 c = p[lane + 64];
        float partial = a.x * ta.x + a.y * ta.y + a.z * ta.z + a.w * ta.w
                      + c.x * tb.x + c.y * tb.y + c.z * tb.z + c.w * tb.w;
#pragma unroll
        for (int m = 32; m; m >>= 1) partial += __shfl_xor(partial, m, 64);
        if (lane == 0) scores[(size_t)b * SS + s] = partial + bs;
    }
}

// row softmax over S=4096, one block of 1024 threads per row (float4/thread)
__global__ __launch_bounds__(1024) void softmax_kernel(const float* __restrict__ scores,
                                                       float* __restrict__ out) {
    __shared__ float red[16];
    const int b   = blockIdx.x;
    const int tid = threadIdx.x;
    const int wave = tid >> 6, lane = tid & 63;

    const float4 v = ((const float4*)(scores + (size_t)b * SS))[tid];

    // --- max reduce ---
    float m = fmaxf(fmaxf(v.x, v.y), fmaxf(v.z, v.w));
#pragma unroll
    for (int k = 32; k; k >>= 1) m = fmaxf(m, __shfl_xor(m, k, 64));
    if (lane == 0) red[wave] = m;
    __syncthreads();
    if (tid < 16) {
        float x = red[tid];
#pragma unroll
        for (int k = 8; k; k >>= 1) x = fmaxf(x, __shfl_xor(x, k, 16));
        if (tid == 0) red[0] = x;
    }
    __syncthreads();
    m = red[0];
    __syncthreads();   // protect red[] before reuse

    // --- exp + sum reduce ---
    float4 e;
    e.x = __expf(v.x - m); e.y = __expf(v.y - m);
    e.z = __expf(v.z - m); e.w = __expf(v.w - m);
    float s = e.x + e.y + e.z + e.w;
#pragma unroll
    for (int k = 32; k; k >>= 1) s += __shfl_xor(s, k, 64);
    if (lane == 0) red[wave] = s;
    __syncthreads();
    if (tid < 16) {
        float x = red[tid];
#pragma unroll
        for (int k = 8; k; k >>= 1) x += __shfl_xor(x, k, 16);
        if (tid == 0) red[0] = x;
    }
    __syncthreads();
    const float inv = 1.f / red[0];

    float4 o;
    o.x = e.x * inv; o.y = e.y * inv; o.z = e.z * inv; o.w = e.w * inv;
    ((float4*)(out + (size_t)b * SS))[tid] = o;
}

extern "C" void kernel_launch(void* const* d_in, const int* in_sizes, int n_in,
                              void* d_out, int out_size, void* d_ws, size_t ws_size,
                              hipStream_t stream) {
    const float* topic = (const float*)d_in[0];   // [B, D]
    const float* seq   = (const float*)d_in[1];   // [B, S, D]
    const float* W     = (const float*)d_in[2];   // [D, D]
    const float* bias  = (const float*)d_in[3];   // [1]
    float* out = (float*)d_out;                   // [B, S]

    float* t      = (float*)d_ws;                 // B*D floats
    float* scores = t + BB * DD;                  // B*S floats

    tW_kernel<<<dim3(BB * 2), 256, 0, stream>>>(topic, W, t);
    scores_kernel<<<dim3(SS / 32, BB), 256, 0, stream>>>(t, seq, bias, scores);
    softmax_kernel<<<dim3(BB), 1024, 0, stream>>>(scores, out);
}

// Round 2
// 683.579 us; speedup vs baseline: 1.0463x; 1.0463x over previous
//
#include <hip/hip_runtime.h>
#include <math.h>

#define BB 64
#define SS 4096
#define DD 512

// t[b,d] = sum_k topic[b,k] * W[k,d]
// grid: 64 b * 4 d-chunks = 256 blocks; block 256 threads.
// Each block computes 128 d-columns (32 float4 groups), k split into 8 strips.
__global__ __launch_bounds__(256) void tW_kernel(const float* __restrict__ topic,
                                                 const float* __restrict__ W,
                                                 float* __restrict__ t) {
    __shared__ float tp[DD];
    __shared__ float4 part[256];
    const int b      = blockIdx.x >> 2;
    const int dchunk = (blockIdx.x & 3) * 32;   // in float4 units (32 f4 = 128 floats)
    const int dg     = threadIdx.x & 31;        // float4 group within chunk
    const int strip  = threadIdx.x >> 5;        // 0..7, each owns 64 k
    for (int i = threadIdx.x; i < DD; i += 256) tp[i] = topic[b * DD + i];
    __syncthreads();
    const float4* W4 = (const float4*)W;        // row stride 128 float4
    float4 acc = {0.f, 0.f, 0.f, 0.f};
    const int k0 = strip * 64;
#pragma unroll 8
    for (int k = 0; k < 64; ++k) {
        const float s  = tp[k0 + k];
        const float4 w = W4[(size_t)(k0 + k) * 128 + dchunk + dg];
        acc.x += s * w.x; acc.y += s * w.y; acc.z += s * w.z; acc.w += s * w.w;
    }
    part[threadIdx.x] = acc;
    __syncthreads();
    if (threadIdx.x < 32) {
        float4 r = part[threadIdx.x];
#pragma unroll
        for (int st = 1; st < 8; ++st) {
            const float4 q = part[st * 32 + threadIdx.x];
            r.x += q.x; r.y += q.y; r.z += q.z; r.w += q.w;
        }
        ((float4*)(t + b * DD))[dchunk + dg] = r;
    }
}

// scores[b,s] = t[b] . seq[b,s] + bias
// one wave per score, 32 scores/block, 2 scores in flight per wave step.
__global__ __launch_bounds__(256) void scores_kernel(const float* __restrict__ t,
                                                     const float* __restrict__ seq,
                                                     const float* __restrict__ bias,
                                                     float* __restrict__ scores) {
    const int b    = blockIdx.y;
    const int s0   = blockIdx.x << 5;
    const int wave = threadIdx.x >> 6;
    const int lane = threadIdx.x & 63;

    const float4* trow = (const float4*)(t + b * DD);
    const float4 ta = trow[lane];
    const float4 tb = trow[lane + 64];
    const float bs = bias[0];

    const float4* base = (const float4*)(seq + ((size_t)b * SS + s0) * DD);
    float* srow = scores + (size_t)b * SS + s0;

#pragma unroll
    for (int j = 0; j < 8; j += 2) {
        const int i0 = wave + 4 * j;   // {w, w+8, w+16, w+24}
        const int i1 = i0 + 4;
        const float4* p0 = base + (size_t)i0 * 128;
        const float4* p1 = base + (size_t)i1 * 128;
        const float4 a0 = p0[lane], c0 = p0[lane + 64];
        const float4 a1 = p1[lane], c1 = p1[lane + 64];
        float r0 = a0.x * ta.x + a0.y * ta.y + a0.z * ta.z + a0.w * ta.w
                 + c0.x * tb.x + c0.y * tb.y + c0.z * tb.z + c0.w * tb.w;
        float r1 = a1.x * ta.x + a1.y * ta.y + a1.z * ta.z + a1.w * ta.w
                 + c1.x * tb.x + c1.y * tb.y + c1.z * tb.z + c1.w * tb.w;
#pragma unroll
        for (int m = 32; m; m >>= 1) {
            r0 += __shfl_xor(r0, m, 64);
            r1 += __shfl_xor(r1, m, 64);
        }
        if (lane == 0) {
            srow[i0] = r0 + bs;
            srow[i1] = r1 + bs;
        }
    }
}

// row softmax over S=4096, one block of 1024 threads per row (float4/thread)
__global__ __launch_bounds__(1024) void softmax_kernel(const float* __restrict__ scores,
                                                       float* __restrict__ out) {
    __shared__ float red[16];
    const int b   = blockIdx.x;
    const int tid = threadIdx.x;
    const int wave = tid >> 6, lane = tid & 63;

    const float4 v = ((const float4*)(scores + (size_t)b * SS))[tid];

    float m = fmaxf(fmaxf(v.x, v.y), fmaxf(v.z, v.w));
#pragma unroll
    for (int k = 32; k; k >>= 1) m = fmaxf(m, __shfl_xor(m, k, 64));
    if (lane == 0) red[wave] = m;
    __syncthreads();
    if (tid < 16) {
        float x = red[tid];
#pragma unroll
        for (int k = 8; k; k >>= 1) x = fmaxf(x, __shfl_xor(x, k, 16));
        if (tid == 0) red[0] = x;
    }
    __syncthreads();
    m = red[0];
    __syncthreads();

    float4 e;
    e.x = __expf(v.x - m); e.y = __expf(v.y - m);
    e.z = __expf(v.z - m); e.w = __expf(v.w - m);
    float s = e.x + e.y + e.z + e.w;
#pragma unroll
    for (int k = 32; k; k >>= 1) s += __shfl_xor(s, k, 64);
    if (lane == 0) red[wave] = s;
    __syncthreads();
    if (tid < 16) {
        float x = red[tid];
#pragma unroll
        for (int k = 8; k; k >>= 1) x += __shfl_xor(x, k, 16);
        if (tid == 0) red[0] = x;
    }
    __syncthreads();
    const float inv = 1.f / red[0];

    float4 o;
    o.x = e.x * inv; o.y = e.y * inv; o.z = e.z * inv; o.w = e.w * inv;
    ((float4*)(out + (size_t)b * SS))[tid] = o;
}

extern "C" void kernel_launch(void* const* d_in, const int* in_sizes, int n_in,
                              void* d_out, int out_size, void* d_ws, size_t ws_size,
                              hipStream_t stream) {
    const float* topic = (const float*)d_in[0];   // [B, D]
    const float* seq   = (const float*)d_in[1];   // [B, S, D]
    const float* W     = (const float*)d_in[2];   // [D, D]
    const float* bias  = (const float*)d_in[3];   // [1]
    float* out = (float*)d_out;                   // [B, S]

    float* t      = (float*)d_ws;                 // B*D floats
    float* scores = t + BB * DD;                  // B*S floats

    tW_kernel<<<dim3(BB * 4), 256, 0, stream>>>(topic, W, t);
    scores_kernel<<<dim3(SS / 32, BB), 256, 0, stream>>>(t, seq, bias, scores);
    softmax_kernel<<<dim3(BB), 1024, 0, stream>>>(scores, out);
}